// Round 6
// baseline (797.860 us; speedup 1.0000x reference)
//
#include <hip/hip_runtime.h>
#include <cstdint>
#include <cstddef>

#define NMAX 100000
#define EMAX 300000

typedef __bf16 bf16_t;
typedef __bf16 bf16x8 __attribute__((ext_vector_type(8)));
typedef float f32x4 __attribute__((ext_vector_type(4)));

// Static device scratch (fully rewritten every launch).
__device__ unsigned short g_qs [(size_t)NMAX * 512];   // [q | s] bf16
__device__ unsigned short g_kv [(size_t)NMAX * 512];   // [k | v] bf16
__device__ unsigned short g_eb [(size_t)EMAX * 256];   // e-proj bf16
__device__ unsigned short g_bfB[(size_t)NMAX * 256];   // out_row bf16 (fused1 -> kv2 A)
__device__ unsigned short g_bfW[589824];               // transposed bf16 weights
__device__ float g_bias[2560];                          // concat biases
__device__ int   g_deg [NMAX + 1];
__device__ int   g_rowptr[NMAX + 1];
__device__ int   g_cur [NMAX];
__device__ int2  g_perm2[EMAX];                         // (src, eid) per CSR slot
__device__ int   g_bsum[512];

struct P10 { const float* p[10]; };

__device__ __forceinline__ unsigned short f2bf(float f) {
  unsigned u = __float_as_uint(f);
  return (unsigned short)((u + 0x7fffu + ((u >> 16) & 1u)) >> 16);
}
__device__ __forceinline__ float bf2f(unsigned short h) {
  return __uint_as_float((unsigned)h << 16);
}

// [W0|W1] (each [K,256] f32) -> Wt[NN,K] bf16 transposed; NN=512 or 256.
__global__ __launch_bounds__(256) void wconv2(const float* __restrict__ W0,
                                              const float* __restrict__ W1,
                                              unsigned short* __restrict__ Wt,
                                              int K, int NN) {
  int i = blockIdx.x * 256 + threadIdx.x;
  if (i >= NN * K) return;
  int n = i / K, k = i - n * K;
  const float* W = (n < 256) ? W0 : W1;
  Wt[i] = f2bf(W[(size_t)k * 256 + (n & 255)]);
}

// Concatenate 10 bias vectors (256 each) into g_bias.
__global__ __launch_bounds__(256) void bconcat(P10 b, float* __restrict__ out) {
  int i = blockIdx.x * 256 + threadIdx.x;
  if (i < 2560) out[i] = b.p[i >> 8][i & 255];
}

#define GLL16(gp, lp) __builtin_amdgcn_global_load_lds( \
    (const __attribute__((address_space(1))) void*)(gp), \
    (__attribute__((address_space(3))) void*)(lp), 16, 0, 0)

// C[M,NS](bf16) = bf16(A[M,K]) @ Wt^T + bias ; 128x128 tile, BK=64, 4 waves,
// 16x16x32 bf16 MFMA. A is f32 (AF32: staged f32, converted in frag load)
// or bf16. XOR-swizzled global_load_lds staging both cases.
template <int K, int NS, bool AF32>
__global__ __launch_bounds__(256) void gemm_mfma(const void* __restrict__ Av,
                                                 const unsigned short* __restrict__ Bt,
                                                 const float* __restrict__ bias,
                                                 unsigned short* __restrict__ C, int M) {
  __shared__ __align__(16) char As[AF32 ? 32768 : 16384];
  __shared__ unsigned short Bs[128 * 64];
  const int tid = threadIdx.x;
  const int lane = tid & 63, wid = tid >> 6;
  const int bm = blockIdx.x * 128, bn = blockIdx.y * 128;
  const int wrow = (wid & 1) * 64, wcol = (wid >> 1) * 64;

  f32x4 acc[4][4] = {};

  for (int k0 = 0; k0 < K; k0 += 64) {
    if constexpr (AF32) {
      const float* Af = (const float*)Av;
      const int sl = lane & 15;
#pragma unroll
      for (int r = 0; r < 8; ++r) {
        int row = wid * 32 + r * 4 + (lane >> 4);
        int arow = bm + row; if (arow >= M) arow = M - 1;
        int sw = ((row & 7) << 1) ^ ((row >> 3) & 1);
        int kk = k0 + ((sl ^ sw) << 2);
        GLL16(Af + (size_t)arow * K + kk, As + (size_t)(wid * 32 + r * 4) * 256);
      }
    } else {
      const unsigned short* Af = (const unsigned short*)Av;
      const int sr = lane >> 3, slot = lane & 7;
#pragma unroll
      for (int r = 0; r < 4; ++r) {
        int row = (wid * 4 + r) * 8 + sr;
        int arow = bm + row; if (arow >= M) arow = M - 1;
        int kk = k0 + ((slot ^ (row & 7)) << 3);
        GLL16(Af + (size_t)arow * K + kk, As + (size_t)(wid * 4 + r) * 1024);
      }
    }
    {
      const int sr = lane >> 3, slot = lane & 7;
#pragma unroll
      for (int r = 0; r < 4; ++r) {
        int col = (wid * 4 + r) * 8 + sr;
        int kk = k0 + ((slot ^ (col & 7)) << 3);
        GLL16(Bt + (size_t)(bn + col) * K + kk, (unsigned short*)Bs + (size_t)(wid * 4 + r) * 512);
      }
    }
    __syncthreads();
    const char* Bb = (const char*)Bs;
#pragma unroll
    for (int h = 0; h < 2; ++h) {
      bf16x8 af[4], bfr[4];
      int g = (lane >> 4) + h * 4;
#pragma unroll
      for (int fm = 0; fm < 4; ++fm) {
        int row = wrow + fm * 16 + (lane & 15);
        if constexpr (AF32) {
          int sw = ((row & 7) << 1) ^ ((row >> 3) & 1);
          const char* rp2 = As + (size_t)row * 256;
          float4 f0 = *(const float4*)(rp2 + (((2 * g) ^ sw) << 4));
          float4 f1 = *(const float4*)(rp2 + (((2 * g + 1) ^ sw) << 4));
          bf16x8 a;
          a[0] = (bf16_t)f0.x; a[1] = (bf16_t)f0.y; a[2] = (bf16_t)f0.z; a[3] = (bf16_t)f0.w;
          a[4] = (bf16_t)f1.x; a[5] = (bf16_t)f1.y; a[6] = (bf16_t)f1.z; a[7] = (bf16_t)f1.w;
          af[fm] = a;
        } else {
          af[fm] = *(const bf16x8*)(As + (size_t)row * 128 + ((g ^ (row & 7)) << 4));
        }
      }
#pragma unroll
      for (int fn = 0; fn < 4; ++fn) {
        int col = wcol + fn * 16 + (lane & 15);
        bfr[fn] = *(const bf16x8*)(Bb + (size_t)col * 128 + ((g ^ (col & 7)) << 4));
      }
#pragma unroll
      for (int fm = 0; fm < 4; ++fm)
#pragma unroll
        for (int fn = 0; fn < 4; ++fn)
          acc[fm][fn] = __builtin_amdgcn_mfma_f32_16x16x32_bf16(af[fm], bfr[fn],
                                                                acc[fm][fn], 0, 0, 0);
    }
    __syncthreads();
  }
  // Epilogue: bias + bf16 store, fn innermost for write locality.
  float bv[4];
#pragma unroll
  for (int fn = 0; fn < 4; ++fn) bv[fn] = bias[bn + wcol + fn * 16 + (lane & 15)];
#pragma unroll
  for (int fm = 0; fm < 4; ++fm) {
    int rbase = bm + wrow + fm * 16 + ((lane >> 4) << 2);
#pragma unroll
    for (int j = 0; j < 4; ++j) {
      int row = rbase + j;
      if (row < M) {
        size_t rb = (size_t)row * NS + bn + wcol + (lane & 15);
#pragma unroll
        for (int fn = 0; fn < 4; ++fn)
          C[rb + fn * 16] = f2bf(acc[fm][fn][j] + bv[fn]);
      }
    }
  }
}

// ---------------- CSR build ----------------
__global__ __launch_bounds__(256) void hist_kernel(const int* __restrict__ ei,
                                                   int* __restrict__ deg, int E) {
  int i = blockIdx.x * 256 + threadIdx.x;
  if (i < E) atomicAdd(&deg[ei[E + i]], 1);
}

__global__ __launch_bounds__(256) void scan1(const int* __restrict__ deg,
                                             int* __restrict__ rowptr,
                                             int* __restrict__ bsum, int n) {
  __shared__ int ws[4];
  int i = blockIdx.x * 256 + threadIdx.x;
  int v = (i < n) ? deg[i] : 0;
  int lane = threadIdx.x & 63, wid = threadIdx.x >> 6;
  int inc = v;
#pragma unroll
  for (int o = 1; o < 64; o <<= 1) {
    int t = __shfl_up(inc, o);
    if (lane >= o) inc += t;
  }
  if (lane == 63) ws[wid] = inc;
  __syncthreads();
  int woff = 0;
  if (wid > 0) woff += ws[0];
  if (wid > 1) woff += ws[1];
  if (wid > 2) woff += ws[2];
  if (i < n) rowptr[i] = inc - v + woff;
  if (threadIdx.x == 255) bsum[blockIdx.x] = inc + woff;
}

__global__ __launch_bounds__(512) void scan2(int* __restrict__ bsum, int B) {
  __shared__ int s[512];
  int t = threadIdx.x;
  int v = (t < B) ? bsum[t] : 0;
  s[t] = v;
  __syncthreads();
  for (int o = 1; o < 512; o <<= 1) {
    int a = (t >= o) ? s[t - o] : 0;
    __syncthreads();
    s[t] += a;
    __syncthreads();
  }
  if (t < B) bsum[t] = s[t] - v;
}

__global__ __launch_bounds__(256) void scan3(int* __restrict__ rowptr,
                                             const int* __restrict__ bsum,
                                             const int* __restrict__ deg,
                                             int* __restrict__ cur, int n) {
  int i = blockIdx.x * 256 + threadIdx.x;
  if (i < n) {
    int r = rowptr[i] + bsum[blockIdx.x];
    rowptr[i] = r;
    cur[i] = r;
    if (i == n - 1) rowptr[n] = r + deg[i];
  }
}

__global__ __launch_bounds__(256) void scatter_kernel(const int* __restrict__ ei,
                                                      int* __restrict__ cur,
                                                      int2* __restrict__ perm2, int E) {
  int i = blockIdx.x * 256 + threadIdx.x;
  if (i < E) {
    int s = ei[i];
    int d = ei[E + i];
    int pos = atomicAdd(&cur[d], 1);
    perm2[pos] = make_int2(s, i);
  }
}

// ---------------- Fused attention + skip + residual + LN (bf16 streams) ---
// One wave per dst node, software-pipelined edge loop (prefetch next edge's
// k/v/e while computing current softmax update).
__global__ __launch_bounds__(256) void fused_attn_ln(
    const int* __restrict__ rowptr, const int2* __restrict__ perm2,
    const unsigned short* __restrict__ qs, const unsigned short* __restrict__ kv,
    const unsigned short* __restrict__ eb,
    const float* __restrict__ x,
    const float* __restrict__ gamma, const float* __restrict__ beta,
    float* __restrict__ out, unsigned short* __restrict__ out_bf, int N) {
  int node = blockIdx.x * 4 + (threadIdx.x >> 6);
  if (node >= N) return;
  int lane = threadIdx.x & 63;
  int c4 = lane << 2;
  // Hoisted independent loads (huge latency slack).
  ushort4 qu = *(const ushort4*)(qs + (size_t)node * 512 + c4);
  ushort4 su = *(const ushort4*)(qs + (size_t)node * 512 + 256 + c4);
  size_t base = (size_t)node * 256 + c4;
  float4 xv = *(const float4*)(x + base);
  float4 qv = make_float4(bf2f(qu.x), bf2f(qu.y), bf2f(qu.z), bf2f(qu.w));
  float4 acc = make_float4(0.f, 0.f, 0.f, 0.f);
  float m = -1e30f, den = 0.f;
  int beg = rowptr[node], end = rowptr[node + 1];
  int2 se = (beg < end) ? perm2[beg] : make_int2(0, 0);
  ushort4 ku = *(const ushort4*)(kv + (size_t)se.x * 512 + c4);
  ushort4 vu = *(const ushort4*)(kv + (size_t)se.x * 512 + 256 + c4);
  ushort4 eu = *(const ushort4*)(eb + (size_t)se.y * 256 + c4);
  for (int p_ = beg; p_ < end; ++p_) {
    int2 seN = (p_ + 1 < end) ? perm2[p_ + 1] : se;
    ushort4 kuN = *(const ushort4*)(kv + (size_t)seN.x * 512 + c4);
    ushort4 vuN = *(const ushort4*)(kv + (size_t)seN.x * 512 + 256 + c4);
    ushort4 euN = *(const ushort4*)(eb + (size_t)seN.y * 256 + c4);
    float e0 = bf2f(eu.x), e1 = bf2f(eu.y), e2 = bf2f(eu.z), e3 = bf2f(eu.w);
    float p = qv.x * (bf2f(ku.x) + e0) + qv.y * (bf2f(ku.y) + e1) +
              qv.z * (bf2f(ku.z) + e2) + qv.w * (bf2f(ku.w) + e3);
    p += __shfl_xor(p, 1); p += __shfl_xor(p, 2);
    p += __shfl_xor(p, 4); p += __shfl_xor(p, 8);
    p *= 0.125f;                      // SCALE = 1/sqrt(64)
    float mn = fmaxf(m, p);
    float sc = expf(m - mn);
    float w  = expf(p - mn);
    den = den * sc + w;
    acc.x = acc.x * sc + w * (bf2f(vu.x) + e0);
    acc.y = acc.y * sc + w * (bf2f(vu.y) + e1);
    acc.z = acc.z * sc + w * (bf2f(vu.z) + e2);
    acc.w = acc.w * sc + w * (bf2f(vu.w) + e3);
    m = mn;
    ku = kuN; vu = vuN; eu = euN; se = seN;
  }
  float inv = (den > 0.f) ? 1.0f / den : 0.f;
  float4 val = make_float4(xv.x + bf2f(su.x) + acc.x * inv,
                           xv.y + bf2f(su.y) + acc.y * inv,
                           xv.z + bf2f(su.z) + acc.z * inv,
                           xv.w + bf2f(su.w) + acc.w * inv);
  float t = val.x + val.y + val.z + val.w;
#pragma unroll
  for (int o = 1; o < 64; o <<= 1) t += __shfl_xor(t, o);
  float mean = t * (1.0f / 256.0f);
  float d0 = val.x - mean, d1 = val.y - mean, d2 = val.z - mean, d3 = val.w - mean;
  float ss = d0 * d0 + d1 * d1 + d2 * d2 + d3 * d3;
#pragma unroll
  for (int o = 1; o < 64; o <<= 1) ss += __shfl_xor(ss, o);
  float rstd = rsqrtf(ss * (1.0f / 256.0f) + 1e-5f);
  float4 gv = *(const float4*)(gamma + c4);
  float4 bv = *(const float4*)(beta + c4);
  float4 o4 = make_float4(d0 * rstd * gv.x + bv.x, d1 * rstd * gv.y + bv.y,
                          d2 * rstd * gv.z + bv.z, d3 * rstd * gv.w + bv.w);
  *(float4*)(out + base) = o4;
  if (out_bf) {
    ushort4 ob = make_ushort4(f2bf(o4.x), f2bf(o4.y), f2bf(o4.z), f2bf(o4.w));
    *(ushort4*)(out_bf + base) = ob;
  }
}

extern "C" void kernel_launch(void* const* d_in, const int* in_sizes, int n_in,
                              void* d_out, int out_size, void* d_ws, size_t ws_size,
                              hipStream_t stream) {
  const float* row_x   = (const float*)d_in[0];
  const float* token_x = (const float*)d_in[1];
  const int*   ei1     = (const int*)d_in[2];    // int32 (JAX x64 disabled)
  const float* ea1     = (const float*)d_in[3];
  const int*   ei2     = (const int*)d_in[4];
  const float* ea2     = (const float*)d_in[5];

  const float* W1q = (const float*)d_in[6];  const float* b1q = (const float*)d_in[7];
  const float* W1k = (const float*)d_in[8];  const float* b1k = (const float*)d_in[9];
  const float* W1v = (const float*)d_in[10]; const float* b1v = (const float*)d_in[11];
  const float* W1e = (const float*)d_in[12]; const float* b1e = (const float*)d_in[13];
  const float* W1s = (const float*)d_in[14]; const float* b1s = (const float*)d_in[15];
  const float* W2q = (const float*)d_in[16]; const float* b2q = (const float*)d_in[17];
  const float* W2k = (const float*)d_in[18]; const float* b2k = (const float*)d_in[19];
  const float* W2v = (const float*)d_in[20]; const float* b2v = (const float*)d_in[21];
  const float* W2e = (const float*)d_in[22]; const float* b2e = (const float*)d_in[23];
  const float* W2s = (const float*)d_in[24]; const float* b2s = (const float*)d_in[25];
  const float* row_gamma   = (const float*)d_in[26];
  const float* row_beta    = (const float*)d_in[27];
  const float* token_gamma = (const float*)d_in[28];
  const float* token_beta  = (const float*)d_in[29];

  const int NR = in_sizes[0] / 256;   // 20000
  const int NT = in_sizes[1] / 256;   // 100000
  const int E  = in_sizes[2] / 2;     // 300000

  float* out_row = (float*)d_out;
  float* out_tok = (float*)d_out + (long long)NR * 256;

  void *pqs_, *pkv_, *peb_, *pbfB_, *pbfW_, *pbias_,
       *pdeg_, *prp_, *pcur_, *pperm_, *pbs_;
  hipGetSymbolAddress(&pqs_,  HIP_SYMBOL(g_qs));
  hipGetSymbolAddress(&pkv_,  HIP_SYMBOL(g_kv));
  hipGetSymbolAddress(&peb_,  HIP_SYMBOL(g_eb));
  hipGetSymbolAddress(&pbfB_, HIP_SYMBOL(g_bfB));
  hipGetSymbolAddress(&pbfW_, HIP_SYMBOL(g_bfW));
  hipGetSymbolAddress(&pbias_,HIP_SYMBOL(g_bias));
  hipGetSymbolAddress(&pdeg_, HIP_SYMBOL(g_deg));
  hipGetSymbolAddress(&prp_,  HIP_SYMBOL(g_rowptr));
  hipGetSymbolAddress(&pcur_, HIP_SYMBOL(g_cur));
  hipGetSymbolAddress(&pperm_,HIP_SYMBOL(g_perm2));
  hipGetSymbolAddress(&pbs_,  HIP_SYMBOL(g_bsum));
  unsigned short* qs  = (unsigned short*)pqs_;
  unsigned short* kv  = (unsigned short*)pkv_;
  unsigned short* eb  = (unsigned short*)peb_;
  unsigned short* bfB = (unsigned short*)pbfB_;
  unsigned short* bfW = (unsigned short*)pbfW_;
  float* gbias = (float*)pbias_;
  int*   deg   = (int*)pdeg_;
  int*   rp    = (int*)prp_;
  int*   cur   = (int*)pcur_;
  int2*  perm2 = (int2*)pperm_;
  int*   bsum  = (int*)pbs_;

  // Weight layout in g_bfW (elements): qs1@0, kv1@131072, e1@262144,
  // qs2@294912, kv2@425984, e2@557056.
  unsigned short* Wqs1 = bfW + 0;
  unsigned short* Wkv1 = bfW + 131072;
  unsigned short* We1  = bfW + 262144;
  unsigned short* Wqs2 = bfW + 294912;
  unsigned short* Wkv2 = bfW + 425984;
  unsigned short* We2  = bfW + 557056;
  wconv2<<<512, 256, 0, stream>>>(W1q, W1s, Wqs1, 256, 512);
  wconv2<<<512, 256, 0, stream>>>(W1k, W1v, Wkv1, 256, 512);
  wconv2<<<128, 256, 0, stream>>>(W1e, nullptr, We1, 128, 256);
  wconv2<<<512, 256, 0, stream>>>(W2q, W2s, Wqs2, 256, 512);
  wconv2<<<512, 256, 0, stream>>>(W2k, W2v, Wkv2, 256, 512);
  wconv2<<<128, 256, 0, stream>>>(W2e, nullptr, We2, 128, 256);
  // Bias layout: [b1q|b1s]@0, [b1k|b1v]@512, b1e@1024, [b2q|b2s]@1280,
  // [b2k|b2v]@1792, b2e@2304.
  P10 bp{{b1q, b1s, b1k, b1v, b1e, b2q, b2s, b2k, b2v, b2e}};
  bconcat<<<10, 256, 0, stream>>>(bp, gbias);

  const int egrid = (E + 255) / 256;

  auto csr = [&](const int* ei, int Ndst) {
    hipMemsetAsync(deg, 0, (size_t)(Ndst + 1) * sizeof(int), stream);
    hist_kernel<<<egrid, 256, 0, stream>>>(ei, deg, E);
    int B = (Ndst + 255) / 256;
    scan1<<<B, 256, 0, stream>>>(deg, rp, bsum, Ndst);
    scan2<<<1, 512, 0, stream>>>(bsum, B);
    scan3<<<B, 256, 0, stream>>>(rp, bsum, deg, cur, Ndst);
    scatter_kernel<<<egrid, 256, 0, stream>>>(ei, cur, perm2, E);
  };

  // ---------------- Phase 1: t2r ----------------
  {
    dim3 gqs((NR + 127) / 128, 4), gkv((NT + 127) / 128, 4), ge((E + 127) / 128, 2);
    gemm_mfma<256, 512, true><<<gqs, 256, 0, stream>>>(row_x,   Wqs1, gbias + 0,    qs, NR);
    gemm_mfma<256, 512, true><<<gkv, 256, 0, stream>>>(token_x, Wkv1, gbias + 512,  kv, NT);
    gemm_mfma<128, 256, true><<<ge,  256, 0, stream>>>(ea1,     We1,  gbias + 1024, eb, E);
    csr(ei1, NR);
    fused_attn_ln<<<(NR + 3) / 4, 256, 0, stream>>>(rp, perm2, qs, kv, eb,
                                                    row_x, row_gamma, row_beta,
                                                    out_row, bfB, NR);
  }

  // ---------------- Phase 2: r2t ----------------
  {
    dim3 gqs((NT + 127) / 128, 4), gkv((NR + 127) / 128, 4), ge((E + 127) / 128, 2);
    gemm_mfma<256, 512, true ><<<gqs, 256, 0, stream>>>(token_x, Wqs2, gbias + 1280, qs, NT);
    gemm_mfma<256, 512, false><<<gkv, 256, 0, stream>>>(bfB,     Wkv2, gbias + 1792, kv, NR);
    gemm_mfma<128, 256, true ><<<ge,  256, 0, stream>>>(ea2,     We2,  gbias + 2304, eb, E);
    csr(ei2, NT);
    fused_attn_ln<<<(NT + 3) / 4, 256, 0, stream>>>(rp, perm2, qs, kv, eb,
                                                    token_x, token_gamma, token_beta,
                                                    out_tok, nullptr, NT);
  }
}

// Round 7
// 788.254 us; speedup vs baseline: 1.0122x; 1.0122x over previous
//
#include <hip/hip_runtime.h>
#include <cstdint>
#include <cstddef>

#define NMAX 100000
#define EMAX 300000

typedef __bf16 bf16_t;
typedef __bf16 bf16x8 __attribute__((ext_vector_type(8)));
typedef float f32x4 __attribute__((ext_vector_type(4)));

// Static device scratch (fully rewritten every launch).
__device__ unsigned short g_qs [(size_t)NMAX * 512];   // [q | s] bf16
__device__ unsigned short g_kv [(size_t)NMAX * 512];   // [k | v] bf16
__device__ unsigned short g_eb [(size_t)EMAX * 256];   // e-proj bf16
__device__ unsigned short g_bfB[(size_t)NMAX * 256];   // out_row bf16 (fused1 -> kv2 A)
__device__ unsigned short g_bfW[589824];               // transposed bf16 weights
__device__ float g_bias[2560];                          // concat biases
__device__ int   g_deg [NMAX + 1];
__device__ int   g_rowptr[NMAX + 1];
__device__ int   g_cur [NMAX];
__device__ int2  g_perm2[EMAX];                         // (src, eid) per CSR slot
__device__ int   g_bsum[512];

struct P10 { const float* p[10]; };

__device__ __forceinline__ unsigned short f2bf(float f) {
  unsigned u = __float_as_uint(f);
  return (unsigned short)((u + 0x7fffu + ((u >> 16) & 1u)) >> 16);
}
__device__ __forceinline__ float bf2f(unsigned short h) {
  return __uint_as_float((unsigned)h << 16);
}

// [W0|W1] (each [K,256] f32) -> Wt[NN,K] bf16 transposed; NN=512 or 256.
__global__ __launch_bounds__(256) void wconv2(const float* __restrict__ W0,
                                              const float* __restrict__ W1,
                                              unsigned short* __restrict__ Wt,
                                              int K, int NN) {
  int i = blockIdx.x * 256 + threadIdx.x;
  if (i >= NN * K) return;
  int n = i / K, k = i - n * K;
  const float* W = (n < 256) ? W0 : W1;
  Wt[i] = f2bf(W[(size_t)k * 256 + (n & 255)]);
}

// Concatenate 10 bias vectors (256 each) into g_bias.
__global__ __launch_bounds__(256) void bconcat(P10 b, float* __restrict__ out) {
  int i = blockIdx.x * 256 + threadIdx.x;
  if (i < 2560) out[i] = b.p[i >> 8][i & 255];
}

// ---------------- Barrier-free skinny GEMM ----------------
// C[M,NS](bf16) = A[M,K] @ Wt^T + bias. W-slice (128 cols x K) staged once
// into LDS (XOR swizzle chunk^=(col&7), reg-staged ds_write). Each of 8
// waves streams a 16-row A-strip direct global->frag (f32->bf16 cvt in
// regs when AF32). NO barriers in main loop -> latency hidden by 16
// waves/CU with continuously outstanding loads.
// grid = (NS/128 col-chunks [fastest], ceil(M/128)).
template <int K, int NS, bool AF32>
__global__ __launch_bounds__(512, 4) void gemm_skinny(const void* __restrict__ Av,
                                                      const unsigned short* __restrict__ Wt,
                                                      const float* __restrict__ bias,
                                                      unsigned short* __restrict__ C,
                                                      int M) {
  constexpr int CH = K / 8;            // 16B chunks per W row
  __shared__ __align__(16) unsigned short Wlds[128 * K];
  const int tid = threadIdx.x;
  const int lane = tid & 63, wid = tid >> 6;
  const int colbase = blockIdx.x * 128;
  const int mbase = blockIdx.y * 128;

  // Stage W slice: rows [colbase, colbase+128) of Wt, swizzled.
  {
    const unsigned short* Wg = Wt + (size_t)colbase * K;
#pragma unroll
    for (int it = 0; it < 128 * CH / 512; ++it) {
      int idx = it * 512 + tid;
      int n = idx / CH, c = idx % CH;
      ((bf16x8*)Wlds)[n * CH + (c ^ (n & 7))] = *(const bf16x8*)(Wg + (size_t)n * K + c * 8);
    }
  }
  __syncthreads();

  const int kg = lane >> 4;            // k-group 0..3 within 32-chunk
  int arow = mbase + wid * 16 + (lane & 15);
  if (arow >= M) arow = M - 1;

  f32x4 acc[8] = {};
#pragma unroll
  for (int kc = 0; kc < K / 32; ++kc) {
    bf16x8 af;
    if constexpr (AF32) {
      const float* ap = (const float*)Av + (size_t)arow * K + kc * 32 + kg * 8;
      float4 f0 = *(const float4*)(ap);
      float4 f1 = *(const float4*)(ap + 4);
      af[0] = (bf16_t)f0.x; af[1] = (bf16_t)f0.y; af[2] = (bf16_t)f0.z; af[3] = (bf16_t)f0.w;
      af[4] = (bf16_t)f1.x; af[5] = (bf16_t)f1.y; af[6] = (bf16_t)f1.z; af[7] = (bf16_t)f1.w;
    } else {
      af = *(const bf16x8*)((const unsigned short*)Av + (size_t)arow * K + kc * 32 + kg * 8);
    }
#pragma unroll
    for (int fn = 0; fn < 8; ++fn) {
      int n = fn * 16 + (lane & 15);
      int chunk = kc * 4 + kg;
      bf16x8 bf = ((const bf16x8*)Wlds)[n * CH + (chunk ^ (n & 7))];
      acc[fn] = __builtin_amdgcn_mfma_f32_16x16x32_bf16(af, bf, acc[fn], 0, 0, 0);
    }
  }

  // Epilogue: bias + bf16 store. C/D layout: col=lane&15, row=(lane>>4)*4+j.
#pragma unroll
  for (int fn = 0; fn < 8; ++fn) {
    int colg = colbase + fn * 16 + (lane & 15);
    float bv = bias[colg];
    int rbase = mbase + wid * 16 + ((lane >> 4) << 2);
#pragma unroll
    for (int j = 0; j < 4; ++j) {
      int row = rbase + j;
      if (row < M) C[(size_t)row * NS + colg] = f2bf(acc[fn][j] + bv);
    }
  }
}

// ---------------- CSR build ----------------
__global__ __launch_bounds__(256) void hist_kernel(const int* __restrict__ ei,
                                                   int* __restrict__ deg, int E) {
  int i = blockIdx.x * 256 + threadIdx.x;
  if (i < E) atomicAdd(&deg[ei[E + i]], 1);
}

__global__ __launch_bounds__(256) void scan1(const int* __restrict__ deg,
                                             int* __restrict__ rowptr,
                                             int* __restrict__ bsum, int n) {
  __shared__ int ws[4];
  int i = blockIdx.x * 256 + threadIdx.x;
  int v = (i < n) ? deg[i] : 0;
  int lane = threadIdx.x & 63, wid = threadIdx.x >> 6;
  int inc = v;
#pragma unroll
  for (int o = 1; o < 64; o <<= 1) {
    int t = __shfl_up(inc, o);
    if (lane >= o) inc += t;
  }
  if (lane == 63) ws[wid] = inc;
  __syncthreads();
  int woff = 0;
  if (wid > 0) woff += ws[0];
  if (wid > 1) woff += ws[1];
  if (wid > 2) woff += ws[2];
  if (i < n) rowptr[i] = inc - v + woff;
  if (threadIdx.x == 255) bsum[blockIdx.x] = inc + woff;
}

__global__ __launch_bounds__(512) void scan2(int* __restrict__ bsum, int B) {
  __shared__ int s[512];
  int t = threadIdx.x;
  int v = (t < B) ? bsum[t] : 0;
  s[t] = v;
  __syncthreads();
  for (int o = 1; o < 512; o <<= 1) {
    int a = (t >= o) ? s[t - o] : 0;
    __syncthreads();
    s[t] += a;
    __syncthreads();
  }
  if (t < B) bsum[t] = s[t] - v;
}

__global__ __launch_bounds__(256) void scan3(int* __restrict__ rowptr,
                                             const int* __restrict__ bsum,
                                             const int* __restrict__ deg,
                                             int* __restrict__ cur, int n) {
  int i = blockIdx.x * 256 + threadIdx.x;
  if (i < n) {
    int r = rowptr[i] + bsum[blockIdx.x];
    rowptr[i] = r;
    cur[i] = r;
    if (i == n - 1) rowptr[n] = r + deg[i];
  }
}

__global__ __launch_bounds__(256) void scatter_kernel(const int* __restrict__ ei,
                                                      int* __restrict__ cur,
                                                      int2* __restrict__ perm2, int E) {
  int i = blockIdx.x * 256 + threadIdx.x;
  if (i < E) {
    int s = ei[i];
    int d = ei[E + i];
    int pos = atomicAdd(&cur[d], 1);
    perm2[pos] = make_int2(s, i);
  }
}

// ---------------- Fused attention + skip + residual + LN (bf16 streams) ---
__global__ __launch_bounds__(256) void fused_attn_ln(
    const int* __restrict__ rowptr, const int2* __restrict__ perm2,
    const unsigned short* __restrict__ qs, const unsigned short* __restrict__ kv,
    const unsigned short* __restrict__ eb,
    const float* __restrict__ x,
    const float* __restrict__ gamma, const float* __restrict__ beta,
    float* __restrict__ out, unsigned short* __restrict__ out_bf, int N) {
  int node = blockIdx.x * 4 + (threadIdx.x >> 6);
  if (node >= N) return;
  int lane = threadIdx.x & 63;
  int c4 = lane << 2;
  ushort4 qu = *(const ushort4*)(qs + (size_t)node * 512 + c4);
  ushort4 su = *(const ushort4*)(qs + (size_t)node * 512 + 256 + c4);
  size_t base = (size_t)node * 256 + c4;
  float4 xv = *(const float4*)(x + base);
  float4 qv = make_float4(bf2f(qu.x), bf2f(qu.y), bf2f(qu.z), bf2f(qu.w));
  float4 acc = make_float4(0.f, 0.f, 0.f, 0.f);
  float m = -1e30f, den = 0.f;
  int beg = rowptr[node], end = rowptr[node + 1];
  int2 se = (beg < end) ? perm2[beg] : make_int2(0, 0);
  ushort4 ku = *(const ushort4*)(kv + (size_t)se.x * 512 + c4);
  ushort4 vu = *(const ushort4*)(kv + (size_t)se.x * 512 + 256 + c4);
  ushort4 eu = *(const ushort4*)(eb + (size_t)se.y * 256 + c4);
  for (int p_ = beg; p_ < end; ++p_) {
    int2 seN = (p_ + 1 < end) ? perm2[p_ + 1] : se;
    ushort4 kuN = *(const ushort4*)(kv + (size_t)seN.x * 512 + c4);
    ushort4 vuN = *(const ushort4*)(kv + (size_t)seN.x * 512 + 256 + c4);
    ushort4 euN = *(const ushort4*)(eb + (size_t)seN.y * 256 + c4);
    float e0 = bf2f(eu.x), e1 = bf2f(eu.y), e2 = bf2f(eu.z), e3 = bf2f(eu.w);
    float p = qv.x * (bf2f(ku.x) + e0) + qv.y * (bf2f(ku.y) + e1) +
              qv.z * (bf2f(ku.z) + e2) + qv.w * (bf2f(ku.w) + e3);
    p += __shfl_xor(p, 1); p += __shfl_xor(p, 2);
    p += __shfl_xor(p, 4); p += __shfl_xor(p, 8);
    p *= 0.125f;                      // SCALE = 1/sqrt(64)
    float mn = fmaxf(m, p);
    float sc = expf(m - mn);
    float w  = expf(p - mn);
    den = den * sc + w;
    acc.x = acc.x * sc + w * (bf2f(vu.x) + e0);
    acc.y = acc.y * sc + w * (bf2f(vu.y) + e1);
    acc.z = acc.z * sc + w * (bf2f(vu.z) + e2);
    acc.w = acc.w * sc + w * (bf2f(vu.w) + e3);
    m = mn;
    ku = kuN; vu = vuN; eu = euN; se = seN;
  }
  float inv = (den > 0.f) ? 1.0f / den : 0.f;
  float4 val = make_float4(xv.x + bf2f(su.x) + acc.x * inv,
                           xv.y + bf2f(su.y) + acc.y * inv,
                           xv.z + bf2f(su.z) + acc.z * inv,
                           xv.w + bf2f(su.w) + acc.w * inv);
  float t = val.x + val.y + val.z + val.w;
#pragma unroll
  for (int o = 1; o < 64; o <<= 1) t += __shfl_xor(t, o);
  float mean = t * (1.0f / 256.0f);
  float d0 = val.x - mean, d1 = val.y - mean, d2 = val.z - mean, d3 = val.w - mean;
  float ss = d0 * d0 + d1 * d1 + d2 * d2 + d3 * d3;
#pragma unroll
  for (int o = 1; o < 64; o <<= 1) ss += __shfl_xor(ss, o);
  float rstd = rsqrtf(ss * (1.0f / 256.0f) + 1e-5f);
  float4 gv = *(const float4*)(gamma + c4);
  float4 bv = *(const float4*)(beta + c4);
  float4 o4 = make_float4(d0 * rstd * gv.x + bv.x, d1 * rstd * gv.y + bv.y,
                          d2 * rstd * gv.z + bv.z, d3 * rstd * gv.w + bv.w);
  *(float4*)(out + base) = o4;
  if (out_bf) {
    ushort4 ob = make_ushort4(f2bf(o4.x), f2bf(o4.y), f2bf(o4.z), f2bf(o4.w));
    *(ushort4*)(out_bf + base) = ob;
  }
}

extern "C" void kernel_launch(void* const* d_in, const int* in_sizes, int n_in,
                              void* d_out, int out_size, void* d_ws, size_t ws_size,
                              hipStream_t stream) {
  const float* row_x   = (const float*)d_in[0];
  const float* token_x = (const float*)d_in[1];
  const int*   ei1     = (const int*)d_in[2];    // int32 (JAX x64 disabled)
  const float* ea1     = (const float*)d_in[3];
  const int*   ei2     = (const int*)d_in[4];
  const float* ea2     = (const float*)d_in[5];

  const float* W1q = (const float*)d_in[6];  const float* b1q = (const float*)d_in[7];
  const float* W1k = (const float*)d_in[8];  const float* b1k = (const float*)d_in[9];
  const float* W1v = (const float*)d_in[10]; const float* b1v = (const float*)d_in[11];
  const float* W1e = (const float*)d_in[12]; const float* b1e = (const float*)d_in[13];
  const float* W1s = (const float*)d_in[14]; const float* b1s = (const float*)d_in[15];
  const float* W2q = (const float*)d_in[16]; const float* b2q = (const float*)d_in[17];
  const float* W2k = (const float*)d_in[18]; const float* b2k = (const float*)d_in[19];
  const float* W2v = (const float*)d_in[20]; const float* b2v = (const float*)d_in[21];
  const float* W2e = (const float*)d_in[22]; const float* b2e = (const float*)d_in[23];
  const float* W2s = (const float*)d_in[24]; const float* b2s = (const float*)d_in[25];
  const float* row_gamma   = (const float*)d_in[26];
  const float* row_beta    = (const float*)d_in[27];
  const float* token_gamma = (const float*)d_in[28];
  const float* token_beta  = (const float*)d_in[29];

  const int NR = in_sizes[0] / 256;   // 20000
  const int NT = in_sizes[1] / 256;   // 100000
  const int E  = in_sizes[2] / 2;     // 300000

  float* out_row = (float*)d_out;
  float* out_tok = (float*)d_out + (long long)NR * 256;

  void *pqs_, *pkv_, *peb_, *pbfB_, *pbfW_, *pbias_,
       *pdeg_, *prp_, *pcur_, *pperm_, *pbs_;
  hipGetSymbolAddress(&pqs_,  HIP_SYMBOL(g_qs));
  hipGetSymbolAddress(&pkv_,  HIP_SYMBOL(g_kv));
  hipGetSymbolAddress(&peb_,  HIP_SYMBOL(g_eb));
  hipGetSymbolAddress(&pbfB_, HIP_SYMBOL(g_bfB));
  hipGetSymbolAddress(&pbfW_, HIP_SYMBOL(g_bfW));
  hipGetSymbolAddress(&pbias_,HIP_SYMBOL(g_bias));
  hipGetSymbolAddress(&pdeg_, HIP_SYMBOL(g_deg));
  hipGetSymbolAddress(&prp_,  HIP_SYMBOL(g_rowptr));
  hipGetSymbolAddress(&pcur_, HIP_SYMBOL(g_cur));
  hipGetSymbolAddress(&pperm_,HIP_SYMBOL(g_perm2));
  hipGetSymbolAddress(&pbs_,  HIP_SYMBOL(g_bsum));
  unsigned short* qs  = (unsigned short*)pqs_;
  unsigned short* kv  = (unsigned short*)pkv_;
  unsigned short* eb  = (unsigned short*)peb_;
  unsigned short* bfB = (unsigned short*)pbfB_;
  unsigned short* bfW = (unsigned short*)pbfW_;
  float* gbias = (float*)pbias_;
  int*   deg   = (int*)pdeg_;
  int*   rp    = (int*)prp_;
  int*   cur   = (int*)pcur_;
  int2*  perm2 = (int2*)pperm_;
  int*   bsum  = (int*)pbs_;

  // Weight layout in g_bfW (elements): qs1@0, kv1@131072, e1@262144,
  // qs2@294912, kv2@425984, e2@557056.
  unsigned short* Wqs1 = bfW + 0;
  unsigned short* Wkv1 = bfW + 131072;
  unsigned short* We1  = bfW + 262144;
  unsigned short* Wqs2 = bfW + 294912;
  unsigned short* Wkv2 = bfW + 425984;
  unsigned short* We2  = bfW + 557056;
  wconv2<<<512, 256, 0, stream>>>(W1q, W1s, Wqs1, 256, 512);
  wconv2<<<512, 256, 0, stream>>>(W1k, W1v, Wkv1, 256, 512);
  wconv2<<<128, 256, 0, stream>>>(W1e, nullptr, We1, 128, 256);
  wconv2<<<512, 256, 0, stream>>>(W2q, W2s, Wqs2, 256, 512);
  wconv2<<<512, 256, 0, stream>>>(W2k, W2v, Wkv2, 256, 512);
  wconv2<<<128, 256, 0, stream>>>(W2e, nullptr, We2, 128, 256);
  // Bias layout: [b1q|b1s]@0, [b1k|b1v]@512, b1e@1024, [b2q|b2s]@1280,
  // [b2k|b2v]@1792, b2e@2304.
  P10 bp{{b1q, b1s, b1k, b1v, b1e, b2q, b2s, b2k, b2v, b2e}};
  bconcat<<<10, 256, 0, stream>>>(bp, gbias);

  const int egrid = (E + 255) / 256;

  auto csr = [&](const int* ei, int Ndst) {
    hipMemsetAsync(deg, 0, (size_t)(Ndst + 1) * sizeof(int), stream);
    hist_kernel<<<egrid, 256, 0, stream>>>(ei, deg, E);
    int B = (Ndst + 255) / 256;
    scan1<<<B, 256, 0, stream>>>(deg, rp, bsum, Ndst);
    scan2<<<1, 512, 0, stream>>>(bsum, B);
    scan3<<<B, 256, 0, stream>>>(rp, bsum, deg, cur, Ndst);
    scatter_kernel<<<egrid, 256, 0, stream>>>(ei, cur, perm2, E);
  };

  // ---------------- Phase 1: t2r ----------------
  {
    gemm_skinny<256, 512, true><<<dim3(4, (NR + 127) / 128), 512, 0, stream>>>(
        row_x, Wqs1, gbias + 0, qs, NR);
    gemm_skinny<256, 512, true><<<dim3(4, (NT + 127) / 128), 512, 0, stream>>>(
        token_x, Wkv1, gbias + 512, kv, NT);
    gemm_skinny<128, 256, true><<<dim3(2, (E + 127) / 128), 512, 0, stream>>>(
        ea1, We1, gbias + 1024, eb, E);
    csr(ei1, NR);
    fused_attn_ln<<<(NR + 3) / 4, 256, 0, stream>>>(rp, perm2, qs, kv, eb,
                                                    row_x, row_gamma, row_beta,
                                                    out_row, bfB, NR);
  }

  // ---------------- Phase 2: r2t ----------------
  {
    gemm_skinny<256, 512, true ><<<dim3(4, (NT + 127) / 128), 512, 0, stream>>>(
        token_x, Wqs2, gbias + 1280, qs, NT);
    gemm_skinny<256, 512, false><<<dim3(4, (NR + 127) / 128), 512, 0, stream>>>(
        bfB, Wkv2, gbias + 1792, kv, NR);
    gemm_skinny<128, 256, true ><<<dim3(2, (E + 127) / 128), 512, 0, stream>>>(
        ea2, We2, gbias + 2304, eb, E);
    csr(ei2, NT);
    fused_attn_ln<<<(NT + 3) / 4, 256, 0, stream>>>(rp, perm2, qs, kv, eb,
                                                    token_x, token_gamma, token_beta,
                                                    out_tok, nullptr, NT);
  }
}